// Round 1
// baseline (576.802 us; speedup 1.0000x reference)
//
#include <hip/hip_runtime.h>

#define N_NODES 50000
#define N_EDGES 800000
#define C 64
#define N_GRAPHS 64

// ---------------- workspace layout (bytes, 256-aligned) ----------------
#define OFF_CNT      0u            // N_NODES ints (histogram, then cursor)
#define OFF_ROWPTR   200192u       // N_NODES+1 ints
#define OFF_ESRC     400384u       // N_EDGES ints (src ids bucketed by dst)
#define OFF_AGG      3600384u      // N_NODES*64 floats (also holds h2 in-place)
#define OFF_H1       16400384u     // N_NODES*64 floats
#define OFF_POOLED   29200384u     // N_GRAPHS*2 uints
// total ~29.2 MB

// ---------------- CSR build ----------------
__global__ void hist_kernel(const int* __restrict__ dst, int* __restrict__ cnt) {
    int i = blockIdx.x * blockDim.x + threadIdx.x;
    if (i < N_EDGES) atomicAdd(&cnt[dst[i]], 1);
}

__global__ __launch_bounds__(1024) void scan_kernel(int* __restrict__ cnt,
                                                    int* __restrict__ rowptr) {
    __shared__ int s[1024];
    const int t = threadIdx.x;
    const int CH = (N_NODES + 1023) / 1024;  // 49
    int beg = t * CH;
    int end = beg + CH; if (end > N_NODES) end = N_NODES;
    int local = 0;
    for (int i = beg; i < end && i < N_NODES; i++) local += cnt[i];
    s[t] = local;
    __syncthreads();
    for (int off = 1; off < 1024; off <<= 1) {
        int v = 0;
        if (t >= off) v = s[t - off];
        __syncthreads();
        if (t >= off) s[t] += v;
        __syncthreads();
    }
    int running = s[t] - local;  // exclusive prefix
    for (int i = beg; i < end && i < N_NODES; i++) {
        int c = cnt[i];
        rowptr[i] = running;
        cnt[i] = running;        // cursor init for scatter
        running += c;
    }
    if (beg < N_NODES && end == N_NODES) rowptr[N_NODES] = running;  // == N_EDGES
}

__global__ void scatter_kernel(const int* __restrict__ src, const int* __restrict__ dst,
                               int* __restrict__ cur, int* __restrict__ esrc) {
    int i = blockIdx.x * blockDim.x + threadIdx.x;
    if (i < N_EDGES) {
        int d = dst[i];
        int pos = atomicAdd(&cur[d], 1);
        esrc[pos] = src[i];
    }
}

// ---------------- aggregation: one wave per node, lane = feature ----------------
__global__ __launch_bounds__(256) void agg_kernel(const float* __restrict__ h,
                                                  const int* __restrict__ rowptr,
                                                  const int* __restrict__ esrc,
                                                  float* __restrict__ agg) {
    int wid = (blockIdx.x * blockDim.x + threadIdx.x) >> 6;
    int lane = threadIdx.x & 63;
    if (wid >= N_NODES) return;
    int beg = rowptr[wid], end = rowptr[wid + 1];
    float acc = 0.f;
    int e = beg;
    for (; e + 4 <= end; e += 4) {
        int j0 = esrc[e], j1 = esrc[e + 1], j2 = esrc[e + 2], j3 = esrc[e + 3];
        float a0 = h[(size_t)j0 * C + lane];
        float a1 = h[(size_t)j1 * C + lane];
        float a2 = h[(size_t)j2 * C + lane];
        float a3 = h[(size_t)j3 * C + lane];
        acc += a0; acc += a1; acc += a2; acc += a3;
    }
    for (; e < end; e++) acc += h[(size_t)esrc[e] * C + lane];
    agg[(size_t)wid * C + lane] = acc;
}

// ---------------- fused double-GEMM + bias + relu ----------------
// out = relu(A @ Wr + B @ Wl + bias), M=N_NODES, N=K=64. 64 rows per block.
// Note: `out` may alias B (in-place): each block reads only its own rows into
// LDS (synced) before writing, and rows are block-private.
__global__ __launch_bounds__(256) void gemm_kernel(const float* __restrict__ A,
                                                   const float* __restrict__ B,
                                                   const float* __restrict__ Wr,
                                                   const float* __restrict__ Wl,
                                                   const float* __restrict__ bias,
                                                   float* out) {
    __shared__ float Wrs[64 * 64];
    __shared__ float Wls[64 * 64];
    __shared__ float As[64 * 65];
    __shared__ float Bs[64 * 65];
    const int t = threadIdx.x;
    const int row0 = blockIdx.x * 64;
    // stage weights: 4096 floats each, 16 per thread
    for (int i = t * 4; i < 4096; i += 1024) {
        *(float4*)&Wrs[i] = *(const float4*)&Wr[i];
        *(float4*)&Wls[i] = *(const float4*)&Wl[i];
    }
    const int r = t >> 2;       // 0..63 local row
    const int q = t & 3;        // quarter of the feature dim
    const int grow = row0 + r;
    if (grow < N_NODES) {
        #pragma unroll
        for (int c = 0; c < 4; c++) {
            *(float4*)&As[r * 65 + q * 16 + c * 4] =
                *(const float4*)&A[(size_t)grow * C + q * 16 + c * 4];
            *(float4*)&Bs[r * 65 + q * 16 + c * 4] =
                *(const float4*)&B[(size_t)grow * C + q * 16 + c * 4];
        }
    }
    __syncthreads();
    const int f0 = q * 16;
    float acc[16];
    #pragma unroll
    for (int ff = 0; ff < 16; ff++) acc[ff] = bias[f0 + ff];
    for (int k = 0; k < 64; k++) {
        float a = As[r * 65 + k];
        float b = Bs[r * 65 + k];
        #pragma unroll
        for (int ff = 0; ff < 16; ff++)
            acc[ff] += a * Wrs[k * 64 + f0 + ff] + b * Wls[k * 64 + f0 + ff];
    }
    if (grow < N_NODES) {
        #pragma unroll
        for (int ff = 0; ff < 16; ff += 4) {
            float4 v;
            v.x = fmaxf(acc[ff + 0], 0.f);
            v.y = fmaxf(acc[ff + 1], 0.f);
            v.z = fmaxf(acc[ff + 2], 0.f);
            v.w = fmaxf(acc[ff + 3], 0.f);
            *(float4*)&out[(size_t)grow * C + f0 + ff] = v;
        }
    }
}

// ---------------- head: mid softmax + fc1 + fc2 + segment_max ----------------
__global__ __launch_bounds__(256) void head_kernel(const float* __restrict__ h2,
                                                   const int* __restrict__ batch,
                                                   const float* __restrict__ fc1w,
                                                   const float* __restrict__ fc1b,
                                                   const float* __restrict__ fc2w,
                                                   const float* __restrict__ fc2b,
                                                   float* __restrict__ mid_out,
                                                   unsigned int* __restrict__ pooled) {
    __shared__ float w1[64 * 8];
    __shared__ float b1s[8];
    __shared__ float w2[16];
    __shared__ float b2s[2];
    const int t = threadIdx.x;
    for (int i = t; i < 512; i += 256) w1[i] = fc1w[i];
    if (t < 8) b1s[t] = fc1b[t];
    if (t < 16) w2[t] = fc2w[t];
    if (t < 2) b2s[t] = fc2b[t];
    __syncthreads();
    const int i = blockIdx.x * 256 + t;
    if (i >= N_NODES) return;
    float row[64];
    #pragma unroll
    for (int c = 0; c < 16; c++) {
        float4 v = *(const float4*)&h2[(size_t)i * C + c * 4];
        row[c * 4 + 0] = v.x; row[c * 4 + 1] = v.y;
        row[c * 4 + 2] = v.z; row[c * 4 + 3] = v.w;
    }
    // mid = softmax(row[0..7])
    float m = row[0];
    #pragma unroll
    for (int j = 1; j < 8; j++) m = fmaxf(m, row[j]);
    float ex[8], s = 0.f;
    #pragma unroll
    for (int j = 0; j < 8; j++) { ex[j] = __expf(row[j] - m); s += ex[j]; }
    float inv = 1.f / s;
    #pragma unroll
    for (int j = 0; j < 8; j += 4) {
        float4 v;
        v.x = ex[j + 0] * inv; v.y = ex[j + 1] * inv;
        v.z = ex[j + 2] * inv; v.w = ex[j + 3] * inv;
        *(float4*)&mid_out[(size_t)i * 8 + j] = v;
    }
    // z1 = relu(row @ fc1_w + fc1_b)
    float z1[8];
    #pragma unroll
    for (int o = 0; o < 8; o++) z1[o] = b1s[o];
    for (int k = 0; k < 64; k++) {
        float a = row[k];
        #pragma unroll
        for (int o = 0; o < 8; o++) z1[o] += a * w1[k * 8 + o];
    }
    #pragma unroll
    for (int o = 0; o < 8; o++) z1[o] = fmaxf(z1[o], 0.f);
    // z2 = relu(z1 @ fc2_w + fc2_b)
    float z2[2];
    #pragma unroll
    for (int p = 0; p < 2; p++) {
        float v = b2s[p];
        #pragma unroll
        for (int o = 0; o < 8; o++) v += z1[o] * w2[o * 2 + p];
        z2[p] = fmaxf(v, 0.f);
    }
    // segment_max via uint atomicMax (valid: values >= 0, pooled init 0)
    int b = batch[i];
    atomicMax(&pooled[b * 2 + 0], __float_as_uint(z2[0]));
    atomicMax(&pooled[b * 2 + 1], __float_as_uint(z2[1]));
}

__global__ void final_kernel(const unsigned int* __restrict__ pooled,
                             float* __restrict__ out) {
    int g = threadIdx.x;
    if (g < N_GRAPHS) {
        float v0 = __uint_as_float(pooled[g * 2 + 0]);
        float v1 = __uint_as_float(pooled[g * 2 + 1]);
        float m = fmaxf(v0, v1);
        float e0 = __expf(v0 - m), e1 = __expf(v1 - m);
        float s = e0 + e1;
        out[g * 2 + 0] = e0 / s;
        out[g * 2 + 1] = e1 / s;
    }
}

// ---------------- launch ----------------
extern "C" void kernel_launch(void* const* d_in, const int* in_sizes, int n_in,
                              void* d_out, int out_size, void* d_ws, size_t ws_size,
                              hipStream_t stream) {
    const float* x    = (const float*)d_in[0];
    const int*   ei   = (const int*)d_in[1];
    const int*   batch= (const int*)d_in[2];
    const float* W1r  = (const float*)d_in[3];
    const float* W1l  = (const float*)d_in[4];
    const float* b1   = (const float*)d_in[5];
    const float* W2r  = (const float*)d_in[6];
    const float* W2l  = (const float*)d_in[7];
    const float* b2   = (const float*)d_in[8];
    const float* fc1w = (const float*)d_in[9];
    const float* fc1b = (const float*)d_in[10];
    const float* fc2w = (const float*)d_in[11];
    const float* fc2b = (const float*)d_in[12];

    const int* src = ei;
    const int* dst = ei + N_EDGES;

    char* ws = (char*)d_ws;
    int*   cnt    = (int*)(ws + OFF_CNT);
    int*   rowptr = (int*)(ws + OFF_ROWPTR);
    int*   esrc   = (int*)(ws + OFF_ESRC);
    float* agg    = (float*)(ws + OFF_AGG);    // also h2 (in-place)
    float* h1     = (float*)(ws + OFF_H1);
    unsigned int* pooled = (unsigned int*)(ws + OFF_POOLED);

    float* mid_out = (float*)d_out;                       // 50000*8
    float* fin_out = (float*)d_out + (size_t)N_NODES * 8; // 64*2

    hipMemsetAsync(cnt, 0, N_NODES * sizeof(int), stream);
    hipMemsetAsync(pooled, 0, N_GRAPHS * 2 * sizeof(unsigned int), stream);

    const int EB = (N_EDGES + 255) / 256;
    hist_kernel<<<EB, 256, 0, stream>>>(dst, cnt);
    scan_kernel<<<1, 1024, 0, stream>>>(cnt, rowptr);
    scatter_kernel<<<EB, 256, 0, stream>>>(src, dst, cnt, esrc);

    const int AB = (N_NODES + 3) / 4;     // 4 waves (nodes) per block
    const int GB = (N_NODES + 63) / 64;   // 64 rows per block
    const int HB = (N_NODES + 255) / 256;

    // layer 1
    agg_kernel<<<AB, 256, 0, stream>>>(x, rowptr, esrc, agg);
    gemm_kernel<<<GB, 256, 0, stream>>>(x, agg, W1r, W1l, b1, h1);
    // layer 2 (output written in-place over agg)
    agg_kernel<<<AB, 256, 0, stream>>>(h1, rowptr, esrc, agg);
    gemm_kernel<<<GB, 256, 0, stream>>>(h1, agg, W2r, W2l, b2, agg);
    // head + pooling
    head_kernel<<<HB, 256, 0, stream>>>(agg, batch, fc1w, fc1b, fc2w, fc2b,
                                        mid_out, pooled);
    final_kernel<<<1, 64, 0, stream>>>(pooled, fin_out);
}

// Round 2
// 341.713 us; speedup vs baseline: 1.6880x; 1.6880x over previous
//
#include <hip/hip_runtime.h>

#define N_NODES 50000
#define N_EDGES 800000
#define C 64
#define N_GRAPHS 64

// ---------------- workspace layout (bytes, 256-aligned) ----------------
#define OFF_CNT      0u            // N_NODES ints (histogram, then cursor)
#define OFF_ROWPTR   200192u       // N_NODES+1 ints
#define OFF_ESRC     400384u       // N_EDGES ints (src ids bucketed by dst)
#define OFF_AGG      3600384u      // N_NODES*64 floats (also holds h2 in-place)
#define OFF_H1       16400384u     // N_NODES*64 floats
#define OFF_POOLED   29200384u     // N_GRAPHS*2 uints
// total ~29.2 MB

// ---------------- CSR build ----------------
__global__ void hist_kernel(const int* __restrict__ dst, int* __restrict__ cnt) {
    int i = blockIdx.x * blockDim.x + threadIdx.x;
    if (i < N_EDGES) atomicAdd(&cnt[dst[i]], 1);
}

__global__ __launch_bounds__(1024) void scan_kernel(int* __restrict__ cnt,
                                                    int* __restrict__ rowptr) {
    __shared__ int s[1024];
    const int t = threadIdx.x;
    const int CH = (N_NODES + 1023) / 1024;  // 49
    int beg = t * CH;
    int end = beg + CH; if (end > N_NODES) end = N_NODES;
    int local = 0;
    for (int i = beg; i < end && i < N_NODES; i++) local += cnt[i];
    s[t] = local;
    __syncthreads();
    for (int off = 1; off < 1024; off <<= 1) {
        int v = 0;
        if (t >= off) v = s[t - off];
        __syncthreads();
        if (t >= off) s[t] += v;
        __syncthreads();
    }
    int running = s[t] - local;  // exclusive prefix
    for (int i = beg; i < end && i < N_NODES; i++) {
        int c = cnt[i];
        rowptr[i] = running;
        cnt[i] = running;        // cursor init for scatter
        running += c;
    }
    if (beg < N_NODES && end == N_NODES) rowptr[N_NODES] = running;  // == N_EDGES
}

__global__ void scatter_kernel(const int* __restrict__ src, const int* __restrict__ dst,
                               int* __restrict__ cur, int* __restrict__ esrc) {
    int i = blockIdx.x * blockDim.x + threadIdx.x;
    if (i < N_EDGES) {
        int d = dst[i];
        int pos = atomicAdd(&cur[d], 1);
        esrc[pos] = src[i];
    }
}

// ---------------- aggregation: one wave per node, lane = feature ----------------
__global__ __launch_bounds__(256) void agg_kernel(const float* __restrict__ h,
                                                  const int* __restrict__ rowptr,
                                                  const int* __restrict__ esrc,
                                                  float* __restrict__ agg) {
    int wid = (blockIdx.x * blockDim.x + threadIdx.x) >> 6;
    int lane = threadIdx.x & 63;
    if (wid >= N_NODES) return;
    int beg = rowptr[wid], end = rowptr[wid + 1];
    float acc = 0.f;
    int e = beg;
    for (; e + 4 <= end; e += 4) {
        int j0 = esrc[e], j1 = esrc[e + 1], j2 = esrc[e + 2], j3 = esrc[e + 3];
        float a0 = h[(size_t)j0 * C + lane];
        float a1 = h[(size_t)j1 * C + lane];
        float a2 = h[(size_t)j2 * C + lane];
        float a3 = h[(size_t)j3 * C + lane];
        acc += a0; acc += a1; acc += a2; acc += a3;
    }
    for (; e < end; e++) acc += h[(size_t)esrc[e] * C + lane];
    agg[(size_t)wid * C + lane] = acc;
}

// ---------------- fused double-GEMM + bias + relu ----------------
// out = relu(A @ Wr + B @ Wl + bias), M=N_NODES, N=K=64. 64 rows per block.
// Note: `out` may alias B (in-place): each block reads only its own rows into
// LDS (synced) before writing, and rows are block-private.
__global__ __launch_bounds__(256) void gemm_kernel(const float* __restrict__ A,
                                                   const float* __restrict__ B,
                                                   const float* __restrict__ Wr,
                                                   const float* __restrict__ Wl,
                                                   const float* __restrict__ bias,
                                                   float* out) {
    __shared__ float Wrs[64 * 64];
    __shared__ float Wls[64 * 64];
    __shared__ float As[64 * 65];
    __shared__ float Bs[64 * 65];
    const int t = threadIdx.x;
    const int row0 = blockIdx.x * 64;
    // stage weights: 4096 floats each, 16 per thread
    for (int i = t * 4; i < 4096; i += 1024) {
        *(float4*)&Wrs[i] = *(const float4*)&Wr[i];
        *(float4*)&Wls[i] = *(const float4*)&Wl[i];
    }
    const int r = t >> 2;       // 0..63 local row
    const int q = t & 3;        // quarter of the feature dim
    const int grow = row0 + r;
    if (grow < N_NODES) {
        #pragma unroll
        for (int c = 0; c < 4; c++) {
            *(float4*)&As[r * 65 + q * 16 + c * 4] =
                *(const float4*)&A[(size_t)grow * C + q * 16 + c * 4];
            *(float4*)&Bs[r * 65 + q * 16 + c * 4] =
                *(const float4*)&B[(size_t)grow * C + q * 16 + c * 4];
        }
    }
    __syncthreads();
    const int f0 = q * 16;
    float acc[16];
    #pragma unroll
    for (int ff = 0; ff < 16; ff++) acc[ff] = bias[f0 + ff];
    for (int k = 0; k < 64; k++) {
        float a = As[r * 65 + k];
        float b = Bs[r * 65 + k];
        #pragma unroll
        for (int ff = 0; ff < 16; ff++)
            acc[ff] += a * Wrs[k * 64 + f0 + ff] + b * Wls[k * 64 + f0 + ff];
    }
    if (grow < N_NODES) {
        #pragma unroll
        for (int ff = 0; ff < 16; ff += 4) {
            float4 v;
            v.x = fmaxf(acc[ff + 0], 0.f);
            v.y = fmaxf(acc[ff + 1], 0.f);
            v.z = fmaxf(acc[ff + 2], 0.f);
            v.w = fmaxf(acc[ff + 3], 0.f);
            *(float4*)&out[(size_t)grow * C + f0 + ff] = v;
        }
    }
}

// ---------------- head: mid softmax + fc1 + fc2 + segment_max ----------------
// segment_max is hierarchical: wave shfl-reduce (batch sorted => most waves
// graph-uniform) -> LDS atomicMax -> <=128 global atomicMax per block.
__global__ __launch_bounds__(256) void head_kernel(const float* __restrict__ h2,
                                                   const int* __restrict__ batch,
                                                   const float* __restrict__ fc1w,
                                                   const float* __restrict__ fc1b,
                                                   const float* __restrict__ fc2w,
                                                   const float* __restrict__ fc2b,
                                                   float* __restrict__ mid_out,
                                                   unsigned int* __restrict__ pooled) {
    __shared__ float w1[64 * 8];
    __shared__ float b1s[8];
    __shared__ float w2[16];
    __shared__ float b2s[2];
    __shared__ unsigned int pool_s[N_GRAPHS * 2];
    const int t = threadIdx.x;
    for (int i = t; i < 512; i += 256) w1[i] = fc1w[i];
    if (t < 8) b1s[t] = fc1b[t];
    if (t < 16) w2[t] = fc2w[t];
    if (t < 2) b2s[t] = fc2b[t];
    if (t < N_GRAPHS * 2) pool_s[t] = 0u;
    __syncthreads();
    const int i = blockIdx.x * 256 + t;
    int b = -1;
    unsigned int u0 = 0u, u1 = 0u;
    if (i < N_NODES) {
        float row[64];
        #pragma unroll
        for (int c = 0; c < 16; c++) {
            float4 v = *(const float4*)&h2[(size_t)i * C + c * 4];
            row[c * 4 + 0] = v.x; row[c * 4 + 1] = v.y;
            row[c * 4 + 2] = v.z; row[c * 4 + 3] = v.w;
        }
        // mid = softmax(row[0..7])
        float m = row[0];
        #pragma unroll
        for (int j = 1; j < 8; j++) m = fmaxf(m, row[j]);
        float ex[8], s = 0.f;
        #pragma unroll
        for (int j = 0; j < 8; j++) { ex[j] = __expf(row[j] - m); s += ex[j]; }
        float inv = 1.f / s;
        #pragma unroll
        for (int j = 0; j < 8; j += 4) {
            float4 v;
            v.x = ex[j + 0] * inv; v.y = ex[j + 1] * inv;
            v.z = ex[j + 2] * inv; v.w = ex[j + 3] * inv;
            *(float4*)&mid_out[(size_t)i * 8 + j] = v;
        }
        // z1 = relu(row @ fc1_w + fc1_b)
        float z1[8];
        #pragma unroll
        for (int o = 0; o < 8; o++) z1[o] = b1s[o];
        for (int k = 0; k < 64; k++) {
            float a = row[k];
            #pragma unroll
            for (int o = 0; o < 8; o++) z1[o] += a * w1[k * 8 + o];
        }
        #pragma unroll
        for (int o = 0; o < 8; o++) z1[o] = fmaxf(z1[o], 0.f);
        // z2 = relu(z1 @ fc2_w + fc2_b)
        float z2[2];
        #pragma unroll
        for (int p = 0; p < 2; p++) {
            float v = b2s[p];
            #pragma unroll
            for (int o = 0; o < 8; o++) v += z1[o] * w2[o * 2 + p];
            z2[p] = fmaxf(v, 0.f);
        }
        b = batch[i];
        u0 = __float_as_uint(z2[0]);
        u1 = __float_as_uint(z2[1]);
    }
    // wave-level max reduce (valid uint compare: values >= 0)
    int b_lo = __shfl(b, 0), b_hi = __shfl(b, 63);
    if (b_lo == b_hi && b_lo >= 0) {
        #pragma unroll
        for (int off = 32; off > 0; off >>= 1) {
            unsigned int o0 = __shfl_xor(u0, off);
            unsigned int o1 = __shfl_xor(u1, off);
            u0 = u0 > o0 ? u0 : o0;
            u1 = u1 > o1 ? u1 : o1;
        }
        if ((t & 63) == 0) {
            atomicMax(&pool_s[b * 2 + 0], u0);
            atomicMax(&pool_s[b * 2 + 1], u1);
        }
    } else if (b >= 0) {  // graph-boundary wave: per-lane LDS atomics
        atomicMax(&pool_s[b * 2 + 0], u0);
        atomicMax(&pool_s[b * 2 + 1], u1);
    }
    __syncthreads();
    if (t < N_GRAPHS * 2) {
        unsigned int v = pool_s[t];
        if (v) atomicMax(&pooled[t], v);
    }
}

__global__ void final_kernel(const unsigned int* __restrict__ pooled,
                             float* __restrict__ out) {
    int g = threadIdx.x;
    if (g < N_GRAPHS) {
        float v0 = __uint_as_float(pooled[g * 2 + 0]);
        float v1 = __uint_as_float(pooled[g * 2 + 1]);
        float m = fmaxf(v0, v1);
        float e0 = __expf(v0 - m), e1 = __expf(v1 - m);
        float s = e0 + e1;
        out[g * 2 + 0] = e0 / s;
        out[g * 2 + 1] = e1 / s;
    }
}

// ---------------- launch ----------------
extern "C" void kernel_launch(void* const* d_in, const int* in_sizes, int n_in,
                              void* d_out, int out_size, void* d_ws, size_t ws_size,
                              hipStream_t stream) {
    const float* x    = (const float*)d_in[0];
    const int*   ei   = (const int*)d_in[1];
    const int*   batch= (const int*)d_in[2];
    const float* W1r  = (const float*)d_in[3];
    const float* W1l  = (const float*)d_in[4];
    const float* b1   = (const float*)d_in[5];
    const float* W2r  = (const float*)d_in[6];
    const float* W2l  = (const float*)d_in[7];
    const float* b2   = (const float*)d_in[8];
    const float* fc1w = (const float*)d_in[9];
    const float* fc1b = (const float*)d_in[10];
    const float* fc2w = (const float*)d_in[11];
    const float* fc2b = (const float*)d_in[12];

    const int* src = ei;
    const int* dst = ei + N_EDGES;

    char* ws = (char*)d_ws;
    int*   cnt    = (int*)(ws + OFF_CNT);
    int*   rowptr = (int*)(ws + OFF_ROWPTR);
    int*   esrc   = (int*)(ws + OFF_ESRC);
    float* agg    = (float*)(ws + OFF_AGG);    // also h2 (in-place)
    float* h1     = (float*)(ws + OFF_H1);
    unsigned int* pooled = (unsigned int*)(ws + OFF_POOLED);

    float* mid_out = (float*)d_out;                       // 50000*8
    float* fin_out = (float*)d_out + (size_t)N_NODES * 8; // 64*2

    hipMemsetAsync(cnt, 0, N_NODES * sizeof(int), stream);
    hipMemsetAsync(pooled, 0, N_GRAPHS * 2 * sizeof(unsigned int), stream);

    const int EB = (N_EDGES + 255) / 256;
    hist_kernel<<<EB, 256, 0, stream>>>(dst, cnt);
    scan_kernel<<<1, 1024, 0, stream>>>(cnt, rowptr);
    scatter_kernel<<<EB, 256, 0, stream>>>(src, dst, cnt, esrc);

    const int AB = (N_NODES + 3) / 4;     // 4 waves (nodes) per block
    const int GB = (N_NODES + 63) / 64;   // 64 rows per block
    const int HB = (N_NODES + 255) / 256;

    // layer 1
    agg_kernel<<<AB, 256, 0, stream>>>(x, rowptr, esrc, agg);
    gemm_kernel<<<GB, 256, 0, stream>>>(x, agg, W1r, W1l, b1, h1);
    // layer 2 (output written in-place over agg)
    agg_kernel<<<AB, 256, 0, stream>>>(h1, rowptr, esrc, agg);
    gemm_kernel<<<GB, 256, 0, stream>>>(h1, agg, W2r, W2l, b2, agg);
    // head + pooling
    head_kernel<<<HB, 256, 0, stream>>>(agg, batch, fc1w, fc1b, fc2w, fc2b,
                                        mid_out, pooled);
    final_kernel<<<1, 64, 0, stream>>>(pooled, fin_out);
}

// Round 3
// 239.497 us; speedup vs baseline: 2.4084x; 1.4268x over previous
//
#include <hip/hip_runtime.h>

#define N_NODES 50000
#define N_EDGES 800000
#define C 64
#define N_GRAPHS 64
#define SCAN_BLK 256
#define N_CHUNKS ((N_NODES + SCAN_BLK - 1) / SCAN_BLK)   // 196

// ---------------- workspace layout (bytes, 256-aligned) ----------------
#define OFF_CNT      0u            // N_NODES ints (histogram, then cursor)
#define OFF_ROWPTR   200192u       // N_NODES+1 ints
#define OFF_ESRC     400384u       // N_EDGES ints (src ids bucketed by dst)
                                   //   (also reused as `partials` during scan)
#define OFF_AGG      3600384u      // N_NODES*64 floats (also holds h2 in-place)
#define OFF_H1       16400384u     // N_NODES*64 floats
#define OFF_POOLED   29200384u     // N_GRAPHS*2 uints
// total ~29.2 MB

// ---------------- CSR build ----------------
__global__ void hist_kernel(const int* __restrict__ dst, int* __restrict__ cnt) {
    int i = blockIdx.x * blockDim.x + threadIdx.x;
    if (i < N_EDGES) atomicAdd(&cnt[dst[i]], 1);
}

// step 1: per-chunk sums
__global__ __launch_bounds__(256) void chunk_reduce_kernel(const int* __restrict__ cnt,
                                                           int* __restrict__ partials) {
    __shared__ int ws[4];
    const int t = threadIdx.x;
    int i = blockIdx.x * SCAN_BLK + t;
    int v = (i < N_NODES) ? cnt[i] : 0;
    #pragma unroll
    for (int off = 32; off > 0; off >>= 1) v += __shfl_xor(v, off);
    if ((t & 63) == 0) ws[t >> 6] = v;
    __syncthreads();
    if (t == 0) partials[blockIdx.x] = ws[0] + ws[1] + ws[2] + ws[3];
}

// step 2: exclusive scan of the 196 partials (single tiny block)
__global__ __launch_bounds__(256) void scan_partials_kernel(int* __restrict__ partials) {
    __shared__ int s[256];
    const int t = threadIdx.x;
    int v = (t < N_CHUNKS) ? partials[t] : 0;
    s[t] = v;
    __syncthreads();
    for (int off = 1; off < 256; off <<= 1) {
        int x = (t >= off) ? s[t - off] : 0;
        __syncthreads();
        if (t >= off) s[t] += x;
        __syncthreads();
    }
    if (t < N_CHUNKS) partials[t] = s[t] - v;   // exclusive
}

// step 3: rescan each chunk, add chunk offset, emit rowptr + cursor
__global__ __launch_bounds__(256) void chunk_scan_kernel(int* __restrict__ cnt,
                                                         int* __restrict__ rowptr,
                                                         const int* __restrict__ partials) {
    __shared__ int s[256];
    const int t = threadIdx.x;
    const int i = blockIdx.x * SCAN_BLK + t;
    int v = (i < N_NODES) ? cnt[i] : 0;
    s[t] = v;
    __syncthreads();
    for (int off = 1; off < 256; off <<= 1) {
        int x = (t >= off) ? s[t - off] : 0;
        __syncthreads();
        if (t >= off) s[t] += x;
        __syncthreads();
    }
    int excl = s[t] - v + partials[blockIdx.x];
    if (i < N_NODES) {
        rowptr[i] = excl;
        cnt[i] = excl;          // cursor init for scatter
    }
    if (i == 0) rowptr[N_NODES] = N_EDGES;
}

__global__ void scatter_kernel(const int* __restrict__ src, const int* __restrict__ dst,
                               int* __restrict__ cur, int* __restrict__ esrc) {
    int i = blockIdx.x * blockDim.x + threadIdx.x;
    if (i < N_EDGES) {
        int d = dst[i];
        int pos = atomicAdd(&cur[d], 1);
        esrc[pos] = src[i];
    }
}

// ---------------- aggregation: one wave per node, lane = feature ----------------
__global__ __launch_bounds__(256) void agg_kernel(const float* __restrict__ h,
                                                  const int* __restrict__ rowptr,
                                                  const int* __restrict__ esrc,
                                                  float* __restrict__ agg) {
    int wid = (blockIdx.x * blockDim.x + threadIdx.x) >> 6;
    int lane = threadIdx.x & 63;
    if (wid >= N_NODES) return;
    int beg = rowptr[wid], end = rowptr[wid + 1];
    float acc = 0.f;
    int e = beg;
    for (; e + 4 <= end; e += 4) {
        int j0 = esrc[e], j1 = esrc[e + 1], j2 = esrc[e + 2], j3 = esrc[e + 3];
        float a0 = h[(size_t)j0 * C + lane];
        float a1 = h[(size_t)j1 * C + lane];
        float a2 = h[(size_t)j2 * C + lane];
        float a3 = h[(size_t)j3 * C + lane];
        acc += a0; acc += a1; acc += a2; acc += a3;
    }
    for (; e < end; e++) acc += h[(size_t)esrc[e] * C + lane];
    agg[(size_t)wid * C + lane] = acc;
}

// ---------------- fused double-GEMM + bias + relu ----------------
// out = relu(A @ Wr + B @ Wl + bias), M=N_NODES, N=K=64. 64 rows per block.
// `out` may alias B (in-place): each block reads its rows into LDS (synced)
// before writing, and rows are block-private.
__global__ __launch_bounds__(256) void gemm_kernel(const float* __restrict__ A,
                                                   const float* __restrict__ B,
                                                   const float* __restrict__ Wr,
                                                   const float* __restrict__ Wl,
                                                   const float* __restrict__ bias,
                                                   float* out) {
    __shared__ float Wrs[64 * 64];
    __shared__ float Wls[64 * 64];
    __shared__ float As[64 * 65];
    __shared__ float Bs[64 * 65];
    const int t = threadIdx.x;
    const int row0 = blockIdx.x * 64;
    for (int i = t * 4; i < 4096; i += 1024) {
        *(float4*)&Wrs[i] = *(const float4*)&Wr[i];
        *(float4*)&Wls[i] = *(const float4*)&Wl[i];
    }
    const int r = t >> 2;       // 0..63 local row
    const int q = t & 3;        // quarter of the feature dim
    const int grow = row0 + r;
    if (grow < N_NODES) {
        #pragma unroll
        for (int c = 0; c < 4; c++) {
            *(float4*)&As[r * 65 + q * 16 + c * 4] =
                *(const float4*)&A[(size_t)grow * C + q * 16 + c * 4];
            *(float4*)&Bs[r * 65 + q * 16 + c * 4] =
                *(const float4*)&B[(size_t)grow * C + q * 16 + c * 4];
        }
    }
    __syncthreads();
    const int f0 = q * 16;
    float acc[16];
    #pragma unroll
    for (int ff = 0; ff < 16; ff++) acc[ff] = bias[f0 + ff];
    for (int k = 0; k < 64; k++) {
        float a = As[r * 65 + k];
        float b = Bs[r * 65 + k];
        #pragma unroll
        for (int ff = 0; ff < 16; ff++)
            acc[ff] += a * Wrs[k * 64 + f0 + ff] + b * Wls[k * 64 + f0 + ff];
    }
    if (grow < N_NODES) {
        #pragma unroll
        for (int ff = 0; ff < 16; ff += 4) {
            float4 v;
            v.x = fmaxf(acc[ff + 0], 0.f);
            v.y = fmaxf(acc[ff + 1], 0.f);
            v.z = fmaxf(acc[ff + 2], 0.f);
            v.w = fmaxf(acc[ff + 3], 0.f);
            *(float4*)&out[(size_t)grow * C + f0 + ff] = v;
        }
    }
}

// ---------------- head: mid softmax + fc1 + fc2 + segment_max ----------------
__global__ __launch_bounds__(256) void head_kernel(const float* __restrict__ h2,
                                                   const int* __restrict__ batch,
                                                   const float* __restrict__ fc1w,
                                                   const float* __restrict__ fc1b,
                                                   const float* __restrict__ fc2w,
                                                   const float* __restrict__ fc2b,
                                                   float* __restrict__ mid_out,
                                                   unsigned int* __restrict__ pooled) {
    __shared__ float w1[64 * 8];
    __shared__ float b1s[8];
    __shared__ float w2[16];
    __shared__ float b2s[2];
    __shared__ unsigned int pool_s[N_GRAPHS * 2];
    const int t = threadIdx.x;
    for (int i = t; i < 512; i += 256) w1[i] = fc1w[i];
    if (t < 8) b1s[t] = fc1b[t];
    if (t < 16) w2[t] = fc2w[t];
    if (t < 2) b2s[t] = fc2b[t];
    if (t < N_GRAPHS * 2) pool_s[t] = 0u;
    __syncthreads();
    const int i = blockIdx.x * 256 + t;
    int b = -1;
    unsigned int u0 = 0u, u1 = 0u;
    if (i < N_NODES) {
        float row[64];
        #pragma unroll
        for (int c = 0; c < 16; c++) {
            float4 v = *(const float4*)&h2[(size_t)i * C + c * 4];
            row[c * 4 + 0] = v.x; row[c * 4 + 1] = v.y;
            row[c * 4 + 2] = v.z; row[c * 4 + 3] = v.w;
        }
        float m = row[0];
        #pragma unroll
        for (int j = 1; j < 8; j++) m = fmaxf(m, row[j]);
        float ex[8], s = 0.f;
        #pragma unroll
        for (int j = 0; j < 8; j++) { ex[j] = __expf(row[j] - m); s += ex[j]; }
        float inv = 1.f / s;
        #pragma unroll
        for (int j = 0; j < 8; j += 4) {
            float4 v;
            v.x = ex[j + 0] * inv; v.y = ex[j + 1] * inv;
            v.z = ex[j + 2] * inv; v.w = ex[j + 3] * inv;
            *(float4*)&mid_out[(size_t)i * 8 + j] = v;
        }
        float z1[8];
        #pragma unroll
        for (int o = 0; o < 8; o++) z1[o] = b1s[o];
        for (int k = 0; k < 64; k++) {
            float a = row[k];
            #pragma unroll
            for (int o = 0; o < 8; o++) z1[o] += a * w1[k * 8 + o];
        }
        #pragma unroll
        for (int o = 0; o < 8; o++) z1[o] = fmaxf(z1[o], 0.f);
        float z2[2];
        #pragma unroll
        for (int p = 0; p < 2; p++) {
            float v = b2s[p];
            #pragma unroll
            for (int o = 0; o < 8; o++) v += z1[o] * w2[o * 2 + p];
            z2[p] = fmaxf(v, 0.f);
        }
        b = batch[i];
        u0 = __float_as_uint(z2[0]);
        u1 = __float_as_uint(z2[1]);
    }
    // wave-level max reduce (valid uint compare: values >= 0)
    int b_lo = __shfl(b, 0), b_hi = __shfl(b, 63);
    if (b_lo == b_hi && b_lo >= 0) {
        #pragma unroll
        for (int off = 32; off > 0; off >>= 1) {
            unsigned int o0 = __shfl_xor(u0, off);
            unsigned int o1 = __shfl_xor(u1, off);
            u0 = u0 > o0 ? u0 : o0;
            u1 = u1 > o1 ? u1 : o1;
        }
        if ((t & 63) == 0) {
            atomicMax(&pool_s[b * 2 + 0], u0);
            atomicMax(&pool_s[b * 2 + 1], u1);
        }
    } else if (b >= 0) {
        atomicMax(&pool_s[b * 2 + 0], u0);
        atomicMax(&pool_s[b * 2 + 1], u1);
    }
    __syncthreads();
    if (t < N_GRAPHS * 2) {
        unsigned int v = pool_s[t];
        if (v) atomicMax(&pooled[t], v);
    }
}

__global__ void final_kernel(const unsigned int* __restrict__ pooled,
                             float* __restrict__ out) {
    int g = threadIdx.x;
    if (g < N_GRAPHS) {
        float v0 = __uint_as_float(pooled[g * 2 + 0]);
        float v1 = __uint_as_float(pooled[g * 2 + 1]);
        float m = fmaxf(v0, v1);
        float e0 = __expf(v0 - m), e1 = __expf(v1 - m);
        float s = e0 + e1;
        out[g * 2 + 0] = e0 / s;
        out[g * 2 + 1] = e1 / s;
    }
}

// ---------------- launch ----------------
extern "C" void kernel_launch(void* const* d_in, const int* in_sizes, int n_in,
                              void* d_out, int out_size, void* d_ws, size_t ws_size,
                              hipStream_t stream) {
    const float* x    = (const float*)d_in[0];
    const int*   ei   = (const int*)d_in[1];
    const int*   batch= (const int*)d_in[2];
    const float* W1r  = (const float*)d_in[3];
    const float* W1l  = (const float*)d_in[4];
    const float* b1   = (const float*)d_in[5];
    const float* W2r  = (const float*)d_in[6];
    const float* W2l  = (const float*)d_in[7];
    const float* b2   = (const float*)d_in[8];
    const float* fc1w = (const float*)d_in[9];
    const float* fc1b = (const float*)d_in[10];
    const float* fc2w = (const float*)d_in[11];
    const float* fc2b = (const float*)d_in[12];

    const int* src = ei;
    const int* dst = ei + N_EDGES;

    char* ws = (char*)d_ws;
    int*   cnt    = (int*)(ws + OFF_CNT);
    int*   rowptr = (int*)(ws + OFF_ROWPTR);
    int*   esrc   = (int*)(ws + OFF_ESRC);
    int*   partials = (int*)(ws + OFF_ESRC);   // reuse: scatter runs after scan
    float* agg    = (float*)(ws + OFF_AGG);    // also h2 (in-place)
    float* h1     = (float*)(ws + OFF_H1);
    unsigned int* pooled = (unsigned int*)(ws + OFF_POOLED);

    float* mid_out = (float*)d_out;                       // 50000*8
    float* fin_out = (float*)d_out + (size_t)N_NODES * 8; // 64*2

    hipMemsetAsync(cnt, 0, N_NODES * sizeof(int), stream);
    hipMemsetAsync(pooled, 0, N_GRAPHS * 2 * sizeof(unsigned int), stream);

    const int EB = (N_EDGES + 255) / 256;
    hist_kernel<<<EB, 256, 0, stream>>>(dst, cnt);
    chunk_reduce_kernel<<<N_CHUNKS, 256, 0, stream>>>(cnt, partials);
    scan_partials_kernel<<<1, 256, 0, stream>>>(partials);
    chunk_scan_kernel<<<N_CHUNKS, 256, 0, stream>>>(cnt, rowptr, partials);
    scatter_kernel<<<EB, 256, 0, stream>>>(src, dst, cnt, esrc);

    const int AB = (N_NODES + 3) / 4;     // 4 waves (nodes) per block
    const int GB = (N_NODES + 63) / 64;   // 64 rows per block
    const int HB = (N_NODES + 255) / 256;

    // layer 1
    agg_kernel<<<AB, 256, 0, stream>>>(x, rowptr, esrc, agg);
    gemm_kernel<<<GB, 256, 0, stream>>>(x, agg, W1r, W1l, b1, h1);
    // layer 2 (output written in-place over agg)
    agg_kernel<<<AB, 256, 0, stream>>>(h1, rowptr, esrc, agg);
    gemm_kernel<<<GB, 256, 0, stream>>>(h1, agg, W2r, W2l, b2, agg);
    // head + pooling
    head_kernel<<<HB, 256, 0, stream>>>(agg, batch, fc1w, fc1b, fc2w, fc2b,
                                        mid_out, pooled);
    final_kernel<<<1, 64, 0, stream>>>(pooled, fin_out);
}